// Round 4
// baseline (5364.298 us; speedup 1.0000x reference)
//
#include <hip/hip_runtime.h>

#define DD 256
#define KK 8192
#define HW 1024
#define NROWS 16384
#define NELEM 4194304
#define MT 32        // rows per block
#define NT 512       // 8 waves: 4 row-groups x 2 k-halves
#define KT 512       // codes per k-tile (64 lanes x 8 codes)

// ---- exact replication of numpy pairwise_sum (n=256) over squares ----
__device__ __forceinline__ float np_pw128_sq(const float* p) {
  float r[8];
#pragma unroll
  for (int j = 0; j < 8; ++j) r[j] = __fmul_rn(p[j], p[j]);
  for (int i = 8; i < 128; i += 8) {
#pragma unroll
    for (int j = 0; j < 8; ++j)
      r[j] = __fadd_rn(r[j], __fmul_rn(p[i + j], p[i + j]));
  }
  return __fadd_rn(__fadd_rn(__fadd_rn(r[0], r[1]), __fadd_rn(r[2], r[3])),
                   __fadd_rn(__fadd_rn(r[4], r[5]), __fadd_rn(r[6], r[7])));
}

// ---------------- kernel: ||e_k||^2, numpy-exact ----------------
__global__ __launch_bounds__(256) void vq_norms(const float* __restrict__ cb,
                                                float* __restrict__ Bk) {
  int k = blockIdx.x * 256 + threadIdx.x;
  const float* p = cb + (size_t)k * DD;
  Bk[k] = __fadd_rn(np_pw128_sq(p), np_pw128_sq(p + 128));
}

// ---------------- kernel: ||z_n||^2, numpy-exact (strided reads) ----------------
__global__ __launch_bounds__(256) void vq_arow(const float* __restrict__ z,
                                               float* __restrict__ Arow) {
  int n = blockIdx.x * 256 + threadIdx.x;
  int bimg = n >> 10, hw = n & 1023;
  const float* zp = z + (size_t)bimg * DD * HW + hw;
  float h[2];
#pragma unroll
  for (int half = 0; half < 2; ++half) {
    float r[8];
#pragma unroll
    for (int j = 0; j < 8; ++j) {
      float v = zp[(size_t)(half * 128 + j) * HW];
      r[j] = __fmul_rn(v, v);
    }
    for (int i = 8; i < 128; i += 8) {
#pragma unroll
      for (int j = 0; j < 8; ++j) {
        float v = zp[(size_t)(half * 128 + i + j) * HW];
        r[j] = __fadd_rn(r[j], __fmul_rn(v, v));
      }
    }
    h[half] = __fadd_rn(__fadd_rn(__fadd_rn(r[0], r[1]), __fadd_rn(r[2], r[3])),
                        __fadd_rn(__fadd_rn(r[4], r[5]), __fadd_rn(r[6], r[7])));
  }
  Arow[n] = __fadd_rn(h[0], h[1]);
}

// ---------------- kernel: codebook transpose cbT[d][k] = cb[k][d] ----------------
__global__ __launch_bounds__(256) void vq_transpose(const float* __restrict__ cb,
                                                    float* __restrict__ cbT) {
  __shared__ float tile[64][65];
  int k0 = blockIdx.x * 64, d0 = blockIdx.y * 64;
  for (int li = threadIdx.x; li < 64 * 64; li += 256) {
    int kk = li >> 6, dd = li & 63;
    tile[kk][dd] = cb[(size_t)(k0 + kk) * DD + d0 + dd];
  }
  __syncthreads();
  for (int li = threadIdx.x; li < 64 * 64; li += 256) {
    int dd = li >> 6, kk = li & 63;
    cbT[(size_t)(d0 + dd) * KK + k0 + kk] = tile[kk][dd];
  }
}

// ---------------- main: dist + argmin + outputs ----------------
__global__ __launch_bounds__(NT, 4) void vq_main(
    const float* __restrict__ z, const float* __restrict__ cbT,
    const float* __restrict__ cb, const float* __restrict__ Bk,
    const float* __restrict__ Arow, float* __restrict__ out,
    int* __restrict__ hist, float* __restrict__ loss_acc) {
  __shared__ float zt[MT][DD + 4];   // 33.3 KB, staged once, reused in epilogue
  __shared__ float redD[8][8];       // per-wave, per-row best
  __shared__ int redI[8][8];
  __shared__ int kwin[MT];
  __shared__ float lred[8];

  const int t = threadIdx.x;
  const int n0 = blockIdx.x * MT;
  const int bimg = n0 >> 10, hw0 = n0 & 1023;
  const float* zb = z + (size_t)bimg * DD * HW + hw0;

  for (int li = t; li < MT * DD; li += NT) {
    int d = li >> 5, r = li & 31;
    zt[r][d] = zb[d * HW + r];
  }
  __syncthreads();

  const int w = t >> 6;        // wave 0..7
  const int cg = t & 63;       // lane
  const int rg = w & 3;        // row group: rows rg*8 .. rg*8+7
  const int khalf = w >> 2;    // code half: [khalf*4096, +4096)

  float Aj[8];
#pragma unroll
  for (int j = 0; j < 8; ++j) Aj[j] = Arow[n0 + rg * 8 + j];

  float bestD[8];
  int bestI[8];
#pragma unroll
  for (int j = 0; j < 8; ++j) { bestD[j] = 3.4e38f; bestI[j] = 0; }

  for (int tt = 0; tt < 8; ++tt) {   // 8 k-tiles of 512 in my half; no barriers
    const int k0 = khalf * 4096 + tt * KT;
    float acc[8][8];
#pragma unroll
    for (int j = 0; j < 8; ++j)
#pragma unroll
      for (int i = 0; i < 8; ++i) acc[j][i] = 0.f;

    const float* cp = cbT + k0 + cg * 8;   // lane-contiguous coalesced
#pragma unroll 2
    for (int d = 0; d < DD; d += 4) {
      float4 zv[8];
#pragma unroll
      for (int j = 0; j < 8; ++j)
        zv[j] = *(const float4*)&zt[rg * 8 + j][d];   // wave-uniform broadcast
#pragma unroll
      for (int dd = 0; dd < 4; ++dd) {
        float4 cv0 = *(const float4*)(cp + (size_t)(d + dd) * KK);
        float4 cv1 = *(const float4*)(cp + (size_t)(d + dd) * KK + 4);
#pragma unroll
        for (int j = 0; j < 8; ++j) {
          float zs = ((const float*)&zv[j])[dd];  // d-ascending exact chain
          acc[j][0] = fmaf(zs, cv0.x, acc[j][0]);
          acc[j][1] = fmaf(zs, cv0.y, acc[j][1]);
          acc[j][2] = fmaf(zs, cv0.z, acc[j][2]);
          acc[j][3] = fmaf(zs, cv0.w, acc[j][3]);
          acc[j][4] = fmaf(zs, cv1.x, acc[j][4]);
          acc[j][5] = fmaf(zs, cv1.y, acc[j][5]);
          acc[j][6] = fmaf(zs, cv1.z, acc[j][6]);
          acc[j][7] = fmaf(zs, cv1.w, acc[j][7]);
        }
      }
    }
    // dist = fl(fl(A+B) - fl(2*dot)); strict < + ascending k => first-min wins
    float4 Bv0 = *(const float4*)(Bk + k0 + cg * 8);
    float4 Bv1 = *(const float4*)(Bk + k0 + cg * 8 + 4);
    float Bv[8] = {Bv0.x, Bv0.y, Bv0.z, Bv0.w, Bv1.x, Bv1.y, Bv1.z, Bv1.w};
#pragma unroll
    for (int j = 0; j < 8; ++j) {
#pragma unroll
      for (int i = 0; i < 8; ++i) {
        float tmp = __fadd_rn(Aj[j], Bv[i]);
        float dist = __fsub_rn(tmp, __fmul_rn(2.f, acc[j][i]));
        if (dist < bestD[j]) { bestD[j] = dist; bestI[j] = k0 + cg * 8 + i; }
      }
    }
  }

  // wave-level argmin butterfly (min, lower-index-on-tie)
#pragma unroll
  for (int j = 0; j < 8; ++j) {
#pragma unroll
    for (int off = 1; off < 64; off <<= 1) {
      float pd = __shfl_xor(bestD[j], off);
      int pi = __shfl_xor(bestI[j], off);
      if (pd < bestD[j] || (pd == bestD[j] && pi < bestI[j])) {
        bestD[j] = pd; bestI[j] = pi;
      }
    }
  }
  if (cg == 0) {
#pragma unroll
    for (int j = 0; j < 8; ++j) { redD[w][j] = bestD[j]; redI[w][j] = bestI[j]; }
  }
  __syncthreads();
  if (t < MT) {                      // row t: combine khalf 0 (w=rg) & 1 (w=rg+4)
    int trg = t >> 3, j = t & 7;
    float d0 = redD[trg][j], d1 = redD[trg + 4][j];
    int i0 = redI[trg][j], i1 = redI[trg + 4][j];
    int bi = (d1 < d0) ? i1 : i0;    // tie -> lower k half (i0 < i1 always)
    kwin[t] = bi;
    atomicAdd(&hist[bi], 1);
    out[(size_t)NELEM + 1 + n0 + t] = (float)bi;
  }
  __syncthreads();

  // z_q gather + straight-through + loss (zt still holds z_e)
  float lsum = 0.f;
  for (int it = 0; it < MT * DD / NT; ++it) {
    int li = it * NT + t;
    int d = li >> 5, r = li & 31;
    float zq = cb[(size_t)kwin[r] * DD + d];
    float ze = zt[r][d];
    float diff = __fsub_rn(zq, ze);
    float st = __fadd_rn(ze, diff);
    out[(size_t)(bimg * DD + d) * HW + hw0 + r] = st;
    lsum = fmaf(diff, diff, lsum);
  }
#pragma unroll
  for (int off = 32; off > 0; off >>= 1) lsum += __shfl_down(lsum, off);
  if (cg == 0) lred[w] = lsum;
  __syncthreads();
  if (t == 0) {
    float s = 0.f;
#pragma unroll
    for (int i = 0; i < 8; ++i) s += lred[i];
    atomicAdd(loss_acc, s);          // one atomic per block
  }
}

// ---------------- finalize: vq_loss + perplexity ----------------
__global__ __launch_bounds__(256) void vq_final(const int* __restrict__ hist,
                                                const float* __restrict__ loss,
                                                float* __restrict__ out) {
  __shared__ float sred[256];
  int t = threadIdx.x;
  float s = 0.f;
  for (int k = t; k < KK; k += 256) {
    float p = (float)hist[k] * (1.f / 16384.f);
    s += p * logf(p + 1e-10f);
  }
  sred[t] = s;
  __syncthreads();
  for (int off = 128; off > 0; off >>= 1) {
    if (t < off) sred[t] += sred[t + off];
    __syncthreads();
  }
  if (t == 0) {
    float L = loss[0] / (float)NELEM;
    out[NELEM] = 1.25f * L;
    out[(size_t)NELEM + 1 + NROWS] = expf(-sred[0]);
  }
}

extern "C" void kernel_launch(void* const* d_in, const int* in_sizes, int n_in,
                              void* d_out, int out_size, void* d_ws, size_t ws_size,
                              hipStream_t stream) {
  const float* z = (const float*)d_in[0];   // (16,256,32,32) fp32
  const float* cb = (const float*)d_in[1];  // (8192,256) fp32
  float* out = (float*)d_out;               // fp32: [z_q_st | loss | idx | perp]

  int* hist = (int*)d_ws;                   // 8192 ints
  float* loss = (float*)d_ws + 8192;        // 1 float (+pad)
  float* Bk = (float*)d_ws + 8448;          // 8192
  float* Arow = (float*)d_ws + 16640;       // 16384
  float* cbT = (float*)d_ws + 33024;        // 2M floats (8 MB)

  hipMemsetAsync(d_ws, 0, 8448 * sizeof(float), stream);
  vq_transpose<<<dim3(KK / 64, DD / 64), 256, 0, stream>>>(cb, cbT);
  vq_norms<<<KK / 256, 256, 0, stream>>>(cb, Bk);
  vq_arow<<<NROWS / 256, 256, 0, stream>>>(z, Arow);
  vq_main<<<NROWS / MT, NT, 0, stream>>>(z, cbT, cb, Bk, Arow, out, hist, loss);
  vq_final<<<1, 256, 0, stream>>>(hist, loss, out);
}

// Round 5
// 4431.137 us; speedup vs baseline: 1.2106x; 1.2106x over previous
//
#include <hip/hip_runtime.h>

#define DD 256
#define KK 8192
#define HW 1024
#define NROWS 16384
#define NELEM 4194304
#define MT 32        // rows per block
#define NT 256
#define KT 512       // codes per k-tile (64 lanes x 8 codes)

// ---- exact replication of numpy pairwise_sum (n=256) over squares ----
__device__ __forceinline__ float np_pw128_sq(const float* p) {
  float r[8];
#pragma unroll
  for (int j = 0; j < 8; ++j) r[j] = __fmul_rn(p[j], p[j]);
  for (int i = 8; i < 128; i += 8) {
#pragma unroll
    for (int j = 0; j < 8; ++j)
      r[j] = __fadd_rn(r[j], __fmul_rn(p[i + j], p[i + j]));
  }
  return __fadd_rn(__fadd_rn(__fadd_rn(r[0], r[1]), __fadd_rn(r[2], r[3])),
                   __fadd_rn(__fadd_rn(r[4], r[5]), __fadd_rn(r[6], r[7])));
}

// ---------------- kernel: ||e_k||^2, numpy-exact ----------------
__global__ __launch_bounds__(256) void vq_norms(const float* __restrict__ cb,
                                                float* __restrict__ Bk) {
  int k = blockIdx.x * 256 + threadIdx.x;
  const float* p = cb + (size_t)k * DD;
  Bk[k] = __fadd_rn(np_pw128_sq(p), np_pw128_sq(p + 128));
}

// ---------------- kernel: ||z_n||^2, numpy-exact (strided reads) ----------------
__global__ __launch_bounds__(256) void vq_arow(const float* __restrict__ z,
                                               float* __restrict__ Arow) {
  int n = blockIdx.x * 256 + threadIdx.x;
  int bimg = n >> 10, hw = n & 1023;
  const float* zp = z + (size_t)bimg * DD * HW + hw;
  float h[2];
#pragma unroll
  for (int half = 0; half < 2; ++half) {
    float r[8];
#pragma unroll
    for (int j = 0; j < 8; ++j) {
      float v = zp[(size_t)(half * 128 + j) * HW];
      r[j] = __fmul_rn(v, v);
    }
    for (int i = 8; i < 128; i += 8) {
#pragma unroll
      for (int j = 0; j < 8; ++j) {
        float v = zp[(size_t)(half * 128 + i + j) * HW];
        r[j] = __fadd_rn(r[j], __fmul_rn(v, v));
      }
    }
    h[half] = __fadd_rn(__fadd_rn(__fadd_rn(r[0], r[1]), __fadd_rn(r[2], r[3])),
                        __fadd_rn(__fadd_rn(r[4], r[5]), __fadd_rn(r[6], r[7])));
  }
  Arow[n] = __fadd_rn(h[0], h[1]);
}

// ---------------- kernel: codebook transpose cbT[d][k] = cb[k][d] ----------------
__global__ __launch_bounds__(256) void vq_transpose(const float* __restrict__ cb,
                                                    float* __restrict__ cbT) {
  __shared__ float tile[64][65];
  int k0 = blockIdx.x * 64, d0 = blockIdx.y * 64;
  for (int li = threadIdx.x; li < 64 * 64; li += 256) {
    int kk = li >> 6, dd = li & 63;
    tile[kk][dd] = cb[(size_t)(k0 + kk) * DD + d0 + dd];
  }
  __syncthreads();
  for (int li = threadIdx.x; li < 64 * 64; li += 256) {
    int dd = li >> 6, kk = li & 63;
    cbT[(size_t)(d0 + dd) * KK + k0 + kk] = tile[kk][dd];
  }
}

// -------- kernel A: distances + per-(row, k-half) argmin --------
// grid 1024: block b -> rows (b>>1)*32 .. +32, codes [(b&1)*4096, +4096)
__global__ __launch_bounds__(NT, 4) void vq_dist(
    const float* __restrict__ z, const float* __restrict__ cbT,
    const float* __restrict__ Bk, const float* __restrict__ Arow,
    float* __restrict__ wsD, int* __restrict__ wsI) {
  __shared__ float zt[MT][DD + 4];   // 33.3 KB -> 4 blocks/CU

  const int t = threadIdx.x;
  const int n0 = (blockIdx.x >> 1) * MT;
  const int khalf = blockIdx.x & 1;
  const int bimg = n0 >> 10, hw0 = n0 & 1023;
  const float* zb = z + (size_t)bimg * DD * HW + hw0;

  for (int li = t; li < MT * DD; li += NT) {
    int d = li >> 5, r = li & 31;
    zt[r][d] = zb[d * HW + r];
  }
  __syncthreads();

  const int w = t >> 6;        // wave = row group (8 rows)
  const int cg = t & 63;       // lane = 8 consecutive codes

  float Aj[8];
#pragma unroll
  for (int j = 0; j < 8; ++j) Aj[j] = Arow[n0 + w * 8 + j];

  float bestD[8];
  int bestI[8];
#pragma unroll
  for (int j = 0; j < 8; ++j) { bestD[j] = 3.4e38f; bestI[j] = 0; }

  for (int tt = 0; tt < 8; ++tt) {   // 8 k-tiles of 512 in my half, no barriers
    const int k0 = khalf * 4096 + tt * KT;
    float acc[8][8];
#pragma unroll
    for (int j = 0; j < 8; ++j)
#pragma unroll
      for (int i = 0; i < 8; ++i) acc[j][i] = 0.f;

    const float* cp = cbT + k0 + cg * 8;   // lane-contiguous coalesced
#pragma unroll 2
    for (int d = 0; d < DD; d += 4) {
      float4 zv[8];
#pragma unroll
      for (int j = 0; j < 8; ++j)
        zv[j] = *(const float4*)&zt[w * 8 + j][d];   // wave-uniform broadcast
#pragma unroll
      for (int dd = 0; dd < 4; ++dd) {
        float4 cv0 = *(const float4*)(cp + (size_t)(d + dd) * KK);
        float4 cv1 = *(const float4*)(cp + (size_t)(d + dd) * KK + 4);
#pragma unroll
        for (int j = 0; j < 8; ++j) {
          float zs = ((const float*)&zv[j])[dd];  // d-ascending exact chain
          acc[j][0] = fmaf(zs, cv0.x, acc[j][0]);
          acc[j][1] = fmaf(zs, cv0.y, acc[j][1]);
          acc[j][2] = fmaf(zs, cv0.z, acc[j][2]);
          acc[j][3] = fmaf(zs, cv0.w, acc[j][3]);
          acc[j][4] = fmaf(zs, cv1.x, acc[j][4]);
          acc[j][5] = fmaf(zs, cv1.y, acc[j][5]);
          acc[j][6] = fmaf(zs, cv1.z, acc[j][6]);
          acc[j][7] = fmaf(zs, cv1.w, acc[j][7]);
        }
      }
    }
    // dist = fl(fl(A+B) - fl(2*dot)); strict < + ascending k => first-min wins
    float4 Bv0 = *(const float4*)(Bk + k0 + cg * 8);
    float4 Bv1 = *(const float4*)(Bk + k0 + cg * 8 + 4);
    float Bv[8] = {Bv0.x, Bv0.y, Bv0.z, Bv0.w, Bv1.x, Bv1.y, Bv1.z, Bv1.w};
#pragma unroll
    for (int j = 0; j < 8; ++j) {
#pragma unroll
      for (int i = 0; i < 8; ++i) {
        float tmp = __fadd_rn(Aj[j], Bv[i]);
        float dist = __fsub_rn(tmp, __fmul_rn(2.f, acc[j][i]));
        if (dist < bestD[j]) { bestD[j] = dist; bestI[j] = k0 + cg * 8 + i; }
      }
    }
  }

  // wave argmin butterfly: lexicographic (dist, idx) min — assoc+comm, exact
#pragma unroll
  for (int j = 0; j < 8; ++j) {
#pragma unroll
    for (int off = 1; off < 64; off <<= 1) {
      float pd = __shfl_xor(bestD[j], off);
      int pi = __shfl_xor(bestI[j], off);
      if (pd < bestD[j] || (pd == bestD[j] && pi < bestI[j])) {
        bestD[j] = pd; bestI[j] = pi;
      }
    }
  }
  if (cg == 0) {
#pragma unroll
    for (int j = 0; j < 8; ++j) {
      int n = n0 + w * 8 + j;
      wsD[n * 2 + khalf] = bestD[j];
      wsI[n * 2 + khalf] = bestI[j];
    }
  }
}

// -------- kernel B: combine halves + idx/hist + z_q_st + loss --------
__global__ __launch_bounds__(256) void vq_out(
    const float* __restrict__ z, const float* __restrict__ cb,
    const float* __restrict__ wsD, const int* __restrict__ wsI,
    float* __restrict__ out, int* __restrict__ hist,
    float* __restrict__ loss_acc) {
  __shared__ int kwin[MT];
  __shared__ float lred[4];
  const int t = threadIdx.x;
  const int n0 = blockIdx.x * MT;
  const int bimg = n0 >> 10, hw0 = n0 & 1023;

  if (t < MT) {
    int n = n0 + t;
    float d0 = wsD[n * 2], d1 = wsD[n * 2 + 1];
    int i0 = wsI[n * 2], i1 = wsI[n * 2 + 1];
    int bi = (d1 < d0) ? i1 : i0;   // tie -> lower half (i0 < i1 always)
    kwin[t] = bi;
    atomicAdd(&hist[bi], 1);
    out[(size_t)NELEM + 1 + n] = (float)bi;
  }
  __syncthreads();

  const float* zb = z + (size_t)bimg * DD * HW + hw0;
  float lsum = 0.f;
  for (int it = 0; it < MT * DD / 256; ++it) {
    int li = it * 256 + t;
    int d = li >> 5, r = li & 31;
    float ze = zb[d * HW + r];
    float zq = cb[(size_t)kwin[r] * DD + d];
    float diff = __fsub_rn(zq, ze);
    float st = __fadd_rn(ze, diff);        // z_e + (z_q - z_e)
    out[(size_t)(bimg * DD + d) * HW + hw0 + r] = st;
    lsum = fmaf(diff, diff, lsum);
  }
#pragma unroll
  for (int off = 32; off > 0; off >>= 1) lsum += __shfl_down(lsum, off);
  if ((t & 63) == 0) lred[t >> 6] = lsum;
  __syncthreads();
  if (t == 0)
    atomicAdd(loss_acc, ((lred[0] + lred[1]) + (lred[2] + lred[3])));
}

// ---------------- finalize: vq_loss + perplexity ----------------
__global__ __launch_bounds__(256) void vq_final(const int* __restrict__ hist,
                                                const float* __restrict__ loss,
                                                float* __restrict__ out) {
  __shared__ float sred[256];
  int t = threadIdx.x;
  float s = 0.f;
  for (int k = t; k < KK; k += 256) {
    float p = (float)hist[k] * (1.f / 16384.f);
    s += p * logf(p + 1e-10f);
  }
  sred[t] = s;
  __syncthreads();
  for (int off = 128; off > 0; off >>= 1) {
    if (t < off) sred[t] += sred[t + off];
    __syncthreads();
  }
  if (t == 0) {
    float L = loss[0] / (float)NELEM;
    out[NELEM] = 1.25f * L;
    out[(size_t)NELEM + 1 + NROWS] = expf(-sred[0]);
  }
}

extern "C" void kernel_launch(void* const* d_in, const int* in_sizes, int n_in,
                              void* d_out, int out_size, void* d_ws, size_t ws_size,
                              hipStream_t stream) {
  const float* z = (const float*)d_in[0];   // (16,256,32,32) fp32
  const float* cb = (const float*)d_in[1];  // (8192,256) fp32
  float* out = (float*)d_out;               // fp32: [z_q_st | loss | idx | perp]

  int* hist = (int*)d_ws;                   // 8192 ints
  float* loss = (float*)d_ws + 8192;        // 1 float (+pad)
  float* Bk = (float*)d_ws + 8448;          // 8192
  float* Arow = (float*)d_ws + 16640;       // 16384
  float* wsD = (float*)d_ws + 33024;        // 32768 (per row x 2 halves)
  int* wsI = (int*)d_ws + 65792;            // 32768
  float* cbT = (float*)d_ws + 98560;        // 2M floats (8 MB)

  hipMemsetAsync(d_ws, 0, 8448 * sizeof(float), stream);
  vq_transpose<<<dim3(KK / 64, DD / 64), 256, 0, stream>>>(cb, cbT);
  vq_norms<<<KK / 256, 256, 0, stream>>>(cb, Bk);
  vq_arow<<<NROWS / 256, 256, 0, stream>>>(z, Arow);
  vq_dist<<<(NROWS / MT) * 2, NT, 0, stream>>>(z, cbT, Bk, Arow, wsD, wsI);
  vq_out<<<NROWS / MT, 256, 0, stream>>>(z, cb, wsD, wsI, out, hist, loss);
  vq_final<<<1, 256, 0, stream>>>(hist, loss, out);
}

// Round 6
// 1219.926 us; speedup vs baseline: 4.3972x; 3.6323x over previous
//
#include <hip/hip_runtime.h>

#define DD 256
#define KK 8192
#define HW 1024
#define NROWS 16384
#define NELEM 4194304
#define MT 32        // rows per block
#define NT 256
#define KT 512       // codes per k-tile (64 lanes x 8 codes)

// ---- exact replication of numpy pairwise_sum (n=256) over squares ----
__device__ __forceinline__ float np_pw128_sq(const float* p) {
  float r[8];
#pragma unroll
  for (int j = 0; j < 8; ++j) r[j] = __fmul_rn(p[j], p[j]);
  for (int i = 8; i < 128; i += 8) {
#pragma unroll
    for (int j = 0; j < 8; ++j)
      r[j] = __fadd_rn(r[j], __fmul_rn(p[i + j], p[i + j]));
  }
  return __fadd_rn(__fadd_rn(__fadd_rn(r[0], r[1]), __fadd_rn(r[2], r[3])),
                   __fadd_rn(__fadd_rn(r[4], r[5]), __fadd_rn(r[6], r[7])));
}

// ---------------- kernel: ||e_k||^2, numpy-exact ----------------
__global__ __launch_bounds__(256) void vq_norms(const float* __restrict__ cb,
                                                float* __restrict__ Bk) {
  int k = blockIdx.x * 256 + threadIdx.x;
  const float* p = cb + (size_t)k * DD;
  Bk[k] = __fadd_rn(np_pw128_sq(p), np_pw128_sq(p + 128));
}

// ---------------- kernel: ||z_n||^2, numpy-exact (strided reads) ----------------
__global__ __launch_bounds__(256) void vq_arow(const float* __restrict__ z,
                                               float* __restrict__ Arow) {
  int n = blockIdx.x * 256 + threadIdx.x;
  int bimg = n >> 10, hw = n & 1023;
  const float* zp = z + (size_t)bimg * DD * HW + hw;
  float h[2];
#pragma unroll
  for (int half = 0; half < 2; ++half) {
    float r[8];
#pragma unroll
    for (int j = 0; j < 8; ++j) {
      float v = zp[(size_t)(half * 128 + j) * HW];
      r[j] = __fmul_rn(v, v);
    }
    for (int i = 8; i < 128; i += 8) {
#pragma unroll
      for (int j = 0; j < 8; ++j) {
        float v = zp[(size_t)(half * 128 + i + j) * HW];
        r[j] = __fadd_rn(r[j], __fmul_rn(v, v));
      }
    }
    h[half] = __fadd_rn(__fadd_rn(__fadd_rn(r[0], r[1]), __fadd_rn(r[2], r[3])),
                        __fadd_rn(__fadd_rn(r[4], r[5]), __fadd_rn(r[6], r[7])));
  }
  Arow[n] = __fadd_rn(h[0], h[1]);
}

// ---------------- kernel: codebook transpose cbT[d][k] = cb[k][d] ----------------
__global__ __launch_bounds__(256) void vq_transpose(const float* __restrict__ cb,
                                                    float* __restrict__ cbT) {
  __shared__ float tile[64][65];
  int k0 = blockIdx.x * 64, d0 = blockIdx.y * 64;
  for (int li = threadIdx.x; li < 64 * 64; li += 256) {
    int kk = li >> 6, dd = li & 63;
    tile[kk][dd] = cb[(size_t)(k0 + kk) * DD + d0 + dd];
  }
  __syncthreads();
  for (int li = threadIdx.x; li < 64 * 64; li += 256) {
    int dd = li >> 6, kk = li & 63;
    cbT[(size_t)(d0 + dd) * KK + k0 + kk] = tile[kk][dd];
  }
}

// -------- kernel A: distances + per-(row, k-half) argmin --------
// grid 1024: block b -> rows (b>>1)*32 .. +32, codes [(b&1)*4096, +4096)
// NOTE: min-waves/EU MUST stay 2 — at 4 the 128-VGPR cap spills acc[8][8]
// to scratch (rounds 4 & 5: VGPR=64, WRITE_SIZE 9-12 GB, 4-5x slowdown).
__global__ __launch_bounds__(NT, 2) void vq_dist(
    const float* __restrict__ z, const float* __restrict__ cbT,
    const float* __restrict__ Bk, const float* __restrict__ Arow,
    float* __restrict__ wsD, int* __restrict__ wsI) {
  __shared__ float zt[MT][DD + 4];   // 33.3 KB -> 4 blocks/CU (LDS-limited)

  const int t = threadIdx.x;
  const int n0 = (blockIdx.x >> 1) * MT;
  const int khalf = blockIdx.x & 1;
  const int bimg = n0 >> 10, hw0 = n0 & 1023;
  const float* zb = z + (size_t)bimg * DD * HW + hw0;

  for (int li = t; li < MT * DD; li += NT) {
    int d = li >> 5, r = li & 31;
    zt[r][d] = zb[d * HW + r];
  }
  __syncthreads();

  const int w = t >> 6;        // wave = row group (8 rows)
  const int cg = t & 63;       // lane = 8 consecutive codes

  float Aj[8];
#pragma unroll
  for (int j = 0; j < 8; ++j) Aj[j] = Arow[n0 + w * 8 + j];

  float bestD[8];
  int bestI[8];
#pragma unroll
  for (int j = 0; j < 8; ++j) { bestD[j] = 3.4e38f; bestI[j] = 0; }

  for (int tt = 0; tt < 8; ++tt) {   // 8 k-tiles of 512 in my half, no barriers
    const int k0 = khalf * 4096 + tt * KT;
    float acc[8][8];
#pragma unroll
    for (int j = 0; j < 8; ++j)
#pragma unroll
      for (int i = 0; i < 8; ++i) acc[j][i] = 0.f;

    const float* cp = cbT + k0 + cg * 8;   // lane-contiguous coalesced
#pragma unroll 2
    for (int d = 0; d < DD; d += 4) {
      float4 zv[8];
#pragma unroll
      for (int j = 0; j < 8; ++j)
        zv[j] = *(const float4*)&zt[w * 8 + j][d];   // wave-uniform broadcast
#pragma unroll
      for (int dd = 0; dd < 4; ++dd) {
        float4 cv0 = *(const float4*)(cp + (size_t)(d + dd) * KK);
        float4 cv1 = *(const float4*)(cp + (size_t)(d + dd) * KK + 4);
#pragma unroll
        for (int j = 0; j < 8; ++j) {
          float zs = ((const float*)&zv[j])[dd];  // d-ascending exact chain
          acc[j][0] = fmaf(zs, cv0.x, acc[j][0]);
          acc[j][1] = fmaf(zs, cv0.y, acc[j][1]);
          acc[j][2] = fmaf(zs, cv0.z, acc[j][2]);
          acc[j][3] = fmaf(zs, cv0.w, acc[j][3]);
          acc[j][4] = fmaf(zs, cv1.x, acc[j][4]);
          acc[j][5] = fmaf(zs, cv1.y, acc[j][5]);
          acc[j][6] = fmaf(zs, cv1.z, acc[j][6]);
          acc[j][7] = fmaf(zs, cv1.w, acc[j][7]);
        }
      }
    }
    // dist = fl(fl(A+B) - fl(2*dot)); strict < + ascending k => first-min wins
    float4 Bv0 = *(const float4*)(Bk + k0 + cg * 8);
    float4 Bv1 = *(const float4*)(Bk + k0 + cg * 8 + 4);
    float Bv[8] = {Bv0.x, Bv0.y, Bv0.z, Bv0.w, Bv1.x, Bv1.y, Bv1.z, Bv1.w};
#pragma unroll
    for (int j = 0; j < 8; ++j) {
#pragma unroll
      for (int i = 0; i < 8; ++i) {
        float tmp = __fadd_rn(Aj[j], Bv[i]);
        float dist = __fsub_rn(tmp, __fmul_rn(2.f, acc[j][i]));
        if (dist < bestD[j]) { bestD[j] = dist; bestI[j] = k0 + cg * 8 + i; }
      }
    }
  }

  // wave argmin butterfly: lexicographic (dist, idx) min — assoc+comm, exact
#pragma unroll
  for (int j = 0; j < 8; ++j) {
#pragma unroll
    for (int off = 1; off < 64; off <<= 1) {
      float pd = __shfl_xor(bestD[j], off);
      int pi = __shfl_xor(bestI[j], off);
      if (pd < bestD[j] || (pd == bestD[j] && pi < bestI[j])) {
        bestD[j] = pd; bestI[j] = pi;
      }
    }
  }
  if (cg == 0) {
#pragma unroll
    for (int j = 0; j < 8; ++j) {
      int n = n0 + w * 8 + j;
      wsD[n * 2 + khalf] = bestD[j];
      wsI[n * 2 + khalf] = bestI[j];
    }
  }
}

// -------- kernel B: combine halves + idx/hist + z_q_st + loss --------
__global__ __launch_bounds__(256) void vq_out(
    const float* __restrict__ z, const float* __restrict__ cb,
    const float* __restrict__ wsD, const int* __restrict__ wsI,
    float* __restrict__ out, int* __restrict__ hist,
    float* __restrict__ loss_acc) {
  __shared__ int kwin[MT];
  __shared__ float lred[4];
  const int t = threadIdx.x;
  const int n0 = blockIdx.x * MT;
  const int bimg = n0 >> 10, hw0 = n0 & 1023;

  if (t < MT) {
    int n = n0 + t;
    float d0 = wsD[n * 2], d1 = wsD[n * 2 + 1];
    int i0 = wsI[n * 2], i1 = wsI[n * 2 + 1];
    int bi = (d1 < d0) ? i1 : i0;   // tie -> lower half (i0 < i1 always)
    kwin[t] = bi;
    atomicAdd(&hist[bi], 1);
    out[(size_t)NELEM + 1 + n] = (float)bi;
  }
  __syncthreads();

  const float* zb = z + (size_t)bimg * DD * HW + hw0;
  float lsum = 0.f;
  for (int it = 0; it < MT * DD / 256; ++it) {
    int li = it * 256 + t;
    int d = li >> 5, r = li & 31;
    float ze = zb[d * HW + r];
    float zq = cb[(size_t)kwin[r] * DD + d];
    float diff = __fsub_rn(zq, ze);
    float st = __fadd_rn(ze, diff);        // z_e + (z_q - z_e)
    out[(size_t)(bimg * DD + d) * HW + hw0 + r] = st;
    lsum = fmaf(diff, diff, lsum);
  }
#pragma unroll
  for (int off = 32; off > 0; off >>= 1) lsum += __shfl_down(lsum, off);
  if ((t & 63) == 0) lred[t >> 6] = lsum;
  __syncthreads();
  if (t == 0)
    atomicAdd(loss_acc, ((lred[0] + lred[1]) + (lred[2] + lred[3])));
}

// ---------------- finalize: vq_loss + perplexity ----------------
__global__ __launch_bounds__(256) void vq_final(const int* __restrict__ hist,
                                                const float* __restrict__ loss,
                                                float* __restrict__ out) {
  __shared__ float sred[256];
  int t = threadIdx.x;
  float s = 0.f;
  for (int k = t; k < KK; k += 256) {
    float p = (float)hist[k] * (1.f / 16384.f);
    s += p * logf(p + 1e-10f);
  }
  sred[t] = s;
  __syncthreads();
  for (int off = 128; off > 0; off >>= 1) {
    if (t < off) sred[t] += sred[t + off];
    __syncthreads();
  }
  if (t == 0) {
    float L = loss[0] / (float)NELEM;
    out[NELEM] = 1.25f * L;
    out[(size_t)NELEM + 1 + NROWS] = expf(-sred[0]);
  }
}

extern "C" void kernel_launch(void* const* d_in, const int* in_sizes, int n_in,
                              void* d_out, int out_size, void* d_ws, size_t ws_size,
                              hipStream_t stream) {
  const float* z = (const float*)d_in[0];   // (16,256,32,32) fp32
  const float* cb = (const float*)d_in[1];  // (8192,256) fp32
  float* out = (float*)d_out;               // fp32: [z_q_st | loss | idx | perp]

  int* hist = (int*)d_ws;                   // 8192 ints
  float* loss = (float*)d_ws + 8192;        // 1 float (+pad)
  float* Bk = (float*)d_ws + 8448;          // 8192
  float* Arow = (float*)d_ws + 16640;       // 16384
  float* wsD = (float*)d_ws + 33024;        // 32768 (per row x 2 halves)
  int* wsI = (int*)d_ws + 65792;            // 32768
  float* cbT = (float*)d_ws + 98560;        // 2M floats (8 MB)

  hipMemsetAsync(d_ws, 0, 8448 * sizeof(float), stream);
  vq_transpose<<<dim3(KK / 64, DD / 64), 256, 0, stream>>>(cb, cbT);
  vq_norms<<<KK / 256, 256, 0, stream>>>(cb, Bk);
  vq_arow<<<NROWS / 256, 256, 0, stream>>>(z, Arow);
  vq_dist<<<(NROWS / MT) * 2, NT, 0, stream>>>(z, cbT, Bk, Arow, wsD, wsI);
  vq_out<<<NROWS / MT, 256, 0, stream>>>(z, cb, wsD, wsI, out, hist, loss);
  vq_final<<<1, 256, 0, stream>>>(hist, loss, out);
}